// Round 5
// baseline (163.570 us; speedup 1.0000x reference)
//
#include <hip/hip_runtime.h>
#include <hip/hip_bf16.h>
#include <cstdint>
#include <cstddef>

#define B_SZ 2
#define L_SEQ 2048
#define DM 1024
#define NH 16
#define HDIM 64
#define BL (B_SZ * L_SEQ)   // 4096 rows total
#define QKV_N (3 * DM)      // 3072

typedef __attribute__((ext_vector_type(4))) float f32x4;
typedef __attribute__((ext_vector_type(16))) float f32x16;
typedef __attribute__((ext_vector_type(8))) short bf16x8;
typedef __attribute__((ext_vector_type(4))) unsigned int u32x4;
typedef unsigned short u16;
typedef __attribute__((ext_vector_type(4))) unsigned short u16x4;

__device__ __forceinline__ float bf2f(u16 u) {
  union { unsigned int i; float f; } c; c.i = ((unsigned int)u) << 16; return c.f;
}
__device__ __forceinline__ u16 f2bf(float f) {
  union { float f; unsigned int i; } c; c.f = f;
  unsigned int r = c.i + 0x7fffu + ((c.i >> 16) & 1u);  // RNE
  return (u16)(r >> 16);
}

__device__ __forceinline__ void gload_lds16(const void* g, void* l) {
  __builtin_amdgcn_global_load_lds(
      (const __attribute__((address_space(1))) void*)g,
      (__attribute__((address_space(3))) void*)l, 16, 0, 0);
}

__device__ __forceinline__ f32x16 mfma32(bf16x8 a, bf16x8 b, f32x16 c) {
  return __builtin_amdgcn_mfma_f32_32x32x16_bf16(a, b, c, 0, 0, 0);
}

// packed f32 pair -> one u32 of 2 bf16 (lo in [15:0])
__device__ __forceinline__ unsigned cvtpk(float lo, float hi) {
  unsigned r;
  asm("v_cvt_pk_bf16_f32 %0, %1, %2" : "=v"(r) : "v"(lo), "v"(hi));
  return r;
}
// swap upper 32 lanes of a with lower 32 lanes of b (both updated)
__device__ __forceinline__ void plswap(unsigned& a, unsigned& b) {
  asm("v_permlane32_swap_b32 %0, %1" : "+v"(a), "+v"(b));
}

// 8 regs of a 32x32 D-layout group (rows (r&3)+8*(r>>2)+4*hi), BASE=0 or 8,
// -> bf16 B-fragment for mfma32 (verified R3).
template <int BASE>
__device__ __forceinline__ bf16x8 pack_bfrag(const f32x16& v) {
  unsigned a  = cvtpk(v[BASE + 0], v[BASE + 1]);
  unsigned a2 = cvtpk(v[BASE + 2], v[BASE + 3]);
  unsigned b  = cvtpk(v[BASE + 4], v[BASE + 5]);
  unsigned b2 = cvtpk(v[BASE + 6], v[BASE + 7]);
  plswap(a, b);
  plswap(a2, b2);
  u32x4 fw; fw[0] = a; fw[1] = a2; fw[2] = b; fw[3] = b2;
  return __builtin_bit_cast(bf16x8, fw);
}

// 15-op max / sum trees over a f32x16
__device__ __forceinline__ float vmax16(const f32x16& v) {
  float a0 = fmaxf(v[0], v[8]), a1 = fmaxf(v[1], v[9]);
  float a2 = fmaxf(v[2], v[10]), a3 = fmaxf(v[3], v[11]);
  float a4 = fmaxf(v[4], v[12]), a5 = fmaxf(v[5], v[13]);
  float a6 = fmaxf(v[6], v[14]), a7 = fmaxf(v[7], v[15]);
  a0 = fmaxf(a0, a4); a1 = fmaxf(a1, a5); a2 = fmaxf(a2, a6); a3 = fmaxf(a3, a7);
  return fmaxf(fmaxf(a0, a2), fmaxf(a1, a3));
}

__device__ __forceinline__ void maskv(f32x16& v, int hi, int l31) {
#pragma unroll
  for (int r = 0; r < 16; ++r) {
    const int kk = (r & 3) + 8 * (r >> 2) + 4 * hi;  // key offset within chunk
    if (kk > l31) v[r] = -1e30f;
  }
}

// ---------------- fp32 -> bf16 convert ----------------
__global__ __launch_bounds__(256) void cvt_f32_bf16(const float* __restrict__ in,
                                                    u16* __restrict__ out, int n4) {
  int i = blockIdx.x * blockDim.x + threadIdx.x;
  const int stride = gridDim.x * blockDim.x;
  for (; i < n4; i += stride) {
    float4 v = ((const float4*)in)[i];
    u16x4 o;
    o[0] = f2bf(v.x); o[1] = f2bf(v.y); o[2] = f2bf(v.z); o[3] = f2bf(v.w);
    ((u16x4*)out)[i] = o;
  }
}

// ---------------- GEMM: C[M,N] = A[M,K] * B[N,K]^T (bf16 in, fp32 acc) ----
template <bool BF16_OUT>
__global__ __launch_bounds__(256) void gemm_bt(
    const u16* __restrict__ A, const u16* __restrict__ B,
    void* __restrict__ Cv, int M, int N, int K) {
  __shared__ u16 As[128 * 32];
  __shared__ u16 Bs[128 * 32];
  const int tid = threadIdx.x;
  const int lane = tid & 63, w = tid >> 6;
  const int lr = lane & 15, lg = lane >> 4;
  const int wr = w >> 1, wc = w & 1;
  const int bm = blockIdx.y * 128, bn = blockIdx.x * 128;

  f32x4 acc[4][4] = {};

  const int l4 = lane >> 2;
  const int csw = ((lane & 3) ^ ((lane >> 3) & 3)) * 8;
  const size_t aoff0 = (size_t)(bm + (w * 2 + 0) * 16 + l4) * K + csw;
  const size_t aoff1 = (size_t)(bm + (w * 2 + 1) * 16 + l4) * K + csw;
  const size_t boff0 = (size_t)(bn + (w * 2 + 0) * 16 + l4) * K + csw;
  const size_t boff1 = (size_t)(bn + (w * 2 + 1) * 16 + l4) * K + csw;
  u16* As0 = As + (w * 2 + 0) * 512;
  u16* As1 = As + (w * 2 + 1) * 512;
  u16* Bs0 = Bs + (w * 2 + 0) * 512;
  u16* Bs1 = Bs + (w * 2 + 1) * 512;
  const int sw_rd = (lr >> 1) & 3;

  for (int k0 = 0; k0 < K; k0 += 32) {
    gload_lds16(A + aoff0 + k0, As0);
    gload_lds16(A + aoff1 + k0, As1);
    gload_lds16(B + boff0 + k0, Bs0);
    gload_lds16(B + boff1 + k0, Bs1);
    __syncthreads();

    bf16x8 af[4], bfr[4];
#pragma unroll
    for (int mt = 0; mt < 4; ++mt) {
      const int row = wr * 64 + mt * 16 + lr;
      af[mt] = *(const bf16x8*)&As[row * 32 + ((lg ^ sw_rd) * 8)];
    }
#pragma unroll
    for (int nt = 0; nt < 4; ++nt) {
      const int row = wc * 64 + nt * 16 + lr;
      bfr[nt] = *(const bf16x8*)&Bs[row * 32 + ((lg ^ sw_rd) * 8)];
    }
#pragma unroll
    for (int mt = 0; mt < 4; ++mt)
#pragma unroll
      for (int nt = 0; nt < 4; ++nt)
        acc[mt][nt] = __builtin_amdgcn_mfma_f32_16x16x32_bf16(af[mt], bfr[nt],
                                                              acc[mt][nt], 0, 0, 0);
    __syncthreads();
  }

#pragma unroll
  for (int mt = 0; mt < 4; ++mt)
#pragma unroll
    for (int nt = 0; nt < 4; ++nt)
#pragma unroll
      for (int r = 0; r < 4; ++r) {
        const int row = bm + wr * 64 + mt * 16 + lg * 4 + r;
        const int col = bn + wc * 64 + nt * 16 + lr;
        if (BF16_OUT)
          ((u16*)Cv)[(size_t)row * N + col] = f2bf(acc[mt][nt][r]);
        else
          ((float*)Cv)[(size_t)row * N + col] = acc[mt][nt][r];
      }
}

// ---------------- fused causal flash attention, KVBLK=128 -----------------
// 512 blocks: slot=id>>5, bh=id&31; qt = slot<8 ? 15-2*slot : 2*(slot-8)
// (complementary weights: co-resident pairs sum to constant work).
// Block: 4 waves, wave w owns q rows [qt*128 + w*32, +32). nt = qt+1 tiles
// of 128 keys. All staging reg-based (R3 scheme), 1 barrier/iter, no setprio.
// Per-chunk (32-key) wave-uniform causal guards preserve MFMA skipping.
__global__ __launch_bounds__(256) void attn_fused(const u16* __restrict__ qkv,
                                                  u16* __restrict__ aout) {
  __shared__ u16 Kl[2][128 * 64];   // [key][d], slot^=(key&7)
  __shared__ u16 Vt[2][64 * 128];   // [d][key], slot^=g(d)

  const int tid = threadIdx.x;
  const int lane = tid & 63, w = tid >> 6;
  const int l31 = lane & 31, hi = lane >> 5;
  const int id = (int)blockIdx.x;
  const int bh = id & 31, slot = id >> 5;
  const int qt = slot < 8 ? 15 - 2 * slot : 2 * (slot - 8);
  const int b = bh >> 4, h = bh & 15;
  const u16* base = qkv + (size_t)b * L_SEQ * QKV_N;
  const int nt = qt + 1;               // kv tiles (128 keys each)
  const int qrow = qt * 128 + w * 32 + l31;  // this lane's q row

  // ---- K staging (reg): thread -> row tid>>1 (0..127), 64B = slots (tid&1)*4+q
  const int krow = tid >> 1;
  const int kcb = (tid & 1) * 4;
  const int kr7 = krow & 7;
  const u16* gpk_base = base + (size_t)krow * QKV_N + DM + h * HDIM + kcb * 8;
  bf16x8 krg[4];

  // ---- V staging (reg): thread -> d rows vd0, vd0+1; keys vkb*16..+15
  const int vd0 = (tid & 31) * 2;
  const int vkb = tid >> 5;            // 0..7
  const int vge = tid & 7;             // g(vd0)
  const int vgo = (tid & 7) ^ 4;       // g(vd0+1)
  const u16* gpv_base = base + (size_t)(vkb * 16) * QKV_N + 2 * DM + h * HDIM + vd0;
  unsigned int vtmp[16];

  auto issue_loads = [&](int t) {
    const u16* gpk = gpk_base + (size_t)t * 128 * QKV_N;
#pragma unroll
    for (int q = 0; q < 4; ++q) krg[q] = *(const bf16x8*)(gpk + q * 8);
    const u16* gpv = gpv_base + (size_t)t * 128 * QKV_N;
#pragma unroll
    for (int j = 0; j < 16; ++j)
      vtmp[j] = *(const unsigned int*)(gpv + (size_t)j * QKV_N);
  };
  auto write_lds = [&](int buf) {
#pragma unroll
    for (int q = 0; q < 4; ++q)
      *(bf16x8*)&Kl[buf][krow * 64 + (((kcb + q) ^ kr7) * 8)] = krg[q];
    u32x4 lo0, lo1, hi0, hi1;
#pragma unroll
    for (int j = 0; j < 4; ++j) {
      lo0[j] = __builtin_amdgcn_perm(vtmp[2 * j + 1], vtmp[2 * j], 0x05040100u);
      hi0[j] = __builtin_amdgcn_perm(vtmp[2 * j + 1], vtmp[2 * j], 0x07060302u);
      lo1[j] = __builtin_amdgcn_perm(vtmp[2 * j + 9], vtmp[2 * j + 8], 0x05040100u);
      hi1[j] = __builtin_amdgcn_perm(vtmp[2 * j + 9], vtmp[2 * j + 8], 0x07060302u);
    }
    *(u32x4*)&Vt[buf][vd0 * 128 + (((2 * vkb + 0) ^ vge) * 8)] = lo0;
    *(u32x4*)&Vt[buf][vd0 * 128 + (((2 * vkb + 1) ^ vge) * 8)] = lo1;
    *(u32x4*)&Vt[buf][(vd0 + 1) * 128 + (((2 * vkb + 0) ^ vgo) * 8)] = hi0;
    *(u32x4*)&Vt[buf][(vd0 + 1) * 128 + (((2 * vkb + 1) ^ vgo) * 8)] = hi1;
  };

  // ---- Q B-frags: lane holds Q[qrow][dc*16 + hi*8 .. +7], scaled by
  // 0.125 * log2(e) so softmax uses exp2 directly.
  bf16x8 bq[4];
  {
    const u16* qp = base + (size_t)qrow * QKV_N + h * HDIM + hi * 8;
#pragma unroll
    for (int dc = 0; dc < 4; ++dc) {
      bf16x8 tq = *(const bf16x8*)(qp + dc * 16);
#pragma unroll
      for (int i = 0; i < 8; ++i)
        tq[i] = (short)f2bf(bf2f((u16)tq[i]) * 0.18033688f);
      bq[dc] = tq;
    }
  }

  f32x16 acc0 = {}, acc1 = {};  // O^T: d rows [0,32) and [32,64), col q
  float mrow = -1e30f, lrow = 0.f;

  const int vg = ((l31 >> 1) & 7) ^ ((l31 & 1) << 2);  // V^T read swizzle
  const int lsw = l31 & 7;                             // K read swizzle

  issue_loads(0);
  write_lds(0);
  __syncthreads();

  for (int t = 0; t < nt; ++t) {
    const int cur = t & 1;
    if (t + 1 < nt) issue_loads(t + 1);  // HBM latency hides under compute

    // ---- S^T chunks: chunk c covers keys t*128+32c .. +31
    // active iff t<qt (interior) or c<=w (diagonal band)
    f32x16 s0, s1, s2, s3;
#define QKC(c, sv)                                                             \
    if (t < qt || (c) <= w) {                                                  \
      sv = f32x16{};                                                           \
      _Pragma("unroll")                                                        \
      for (int dc = 0; dc < 4; ++dc) {                                         \
        const bf16x8 kk = *(const bf16x8*)                                     \
            &Kl[cur][((c) * 32 + l31) * 64 + (((dc * 2 + hi) ^ lsw) * 8)];     \
        sv = mfma32(kk, bq[dc], sv);                                           \
      }                                                                        \
    } else {                                                                   \
      sv = -1e30f;                                                             \
    }
    QKC(0, s0) QKC(1, s1) QKC(2, s2) QKC(3, s3)
#undef QKC

    // ---- causal mask: diagonal tile, chunk c == w only
    if (t == qt) {
      if (w == 0) maskv(s0, hi, l31);
      else if (w == 1) maskv(s1, hi, l31);
      else if (w == 2) maskv(s2, hi, l31);
      else maskv(s3, hi, l31);
    }

    // ---- tile max (trees + cross-half)
    float px = fmaxf(fmaxf(vmax16(s0), vmax16(s1)), fmaxf(vmax16(s2), vmax16(s3)));
    px = fmaxf(px, __shfl_xor(px, 32));

    // ---- defer-max rescale (T13, THR=8)
    if (!__all(px <= mrow + 8.f)) {
      const float mnew = fmaxf(mrow, px);
      const float alpha = exp2f(mrow - mnew);
      mrow = mnew;
      lrow *= alpha;
#pragma unroll
      for (int i = 0; i < 16; ++i) { acc0[i] *= alpha; acc1[i] *= alpha; }
    }

    // ---- per chunk: exp, partial sum, pack, PV (guarded; skips MFMA+exp)
    float rs = 0.f;
#define PVC(c, sv)                                                             \
    if (t < qt || (c) <= w) {                                                  \
      float t0 = 0.f, t1 = 0.f;                                                \
      _Pragma("unroll")                                                        \
      for (int r = 0; r < 8; ++r) {                                            \
        sv[r] = exp2f(sv[r] - mrow);  t0 += sv[r];                             \
        sv[r + 8] = exp2f(sv[r + 8] - mrow); t1 += sv[r + 8];                  \
      }                                                                        \
      rs += t0 + t1;                                                           \
      const bf16x8 pfa = pack_bfrag<0>(sv);                                    \
      const bf16x8 pfb = pack_bfrag<8>(sv);                                    \
      {                                                                        \
        const int sl = ((4 * (c) + hi) ^ vg) * 8;                              \
        acc0 = mfma32(*(const bf16x8*)&Vt[cur][l31 * 128 + sl], pfa, acc0);    \
        acc1 = mfma32(*(const bf16x8*)&Vt[cur][(32 + l31) * 128 + sl], pfa,    \
                      acc1);                                                   \
      }                                                                        \
      {                                                                        \
        const int sl = ((4 * (c) + 2 + hi) ^ vg) * 8;                          \
        acc0 = mfma32(*(const bf16x8*)&Vt[cur][l31 * 128 + sl], pfb, acc0);    \
        acc1 = mfma32(*(const bf16x8*)&Vt[cur][(32 + l31) * 128 + sl], pfb,    \
                      acc1);                                                   \
      }                                                                        \
    }
    PVC(0, s0) PVC(1, s1) PVC(2, s2) PVC(3, s3)
#undef PVC

    rs += __shfl_xor(rs, 32);
    lrow += rs;

    if (t + 1 < nt) write_lds(cur ^ 1);
    __syncthreads();
  }

  // ---- epilogue: O = O^T / l, repack to d-contiguous frags, 16B stores
  const float inv = 1.f / lrow;
#pragma unroll
  for (int i = 0; i < 16; ++i) { acc0[i] *= inv; acc1[i] *= inv; }
  const bf16x8 of0 = pack_bfrag<0>(acc0);
  const bf16x8 of1 = pack_bfrag<8>(acc0);
  const bf16x8 of2 = pack_bfrag<0>(acc1);
  const bf16x8 of3 = pack_bfrag<8>(acc1);
  u16* op = aout + (size_t)(b * L_SEQ + qrow) * DM + h * HDIM + hi * 8;
  *(bf16x8*)(op + 0)  = of0;
  *(bf16x8*)(op + 16) = of1;
  *(bf16x8*)(op + 32) = of2;
  *(bf16x8*)(op + 48) = of3;
}

// ---------------- host launch ----------------
extern "C" void kernel_launch(void* const* d_in, const int* in_sizes, int n_in,
                              void* d_out, int out_size, void* d_ws, size_t ws_size,
                              hipStream_t stream) {
  (void)in_sizes; (void)n_in; (void)out_size; (void)ws_size;
  const float* x = (const float*)d_in[0];     // [4096][1024]
  const float* wqkv = (const float*)d_in[1];  // [3072][1024]
  const float* wo = (const float*)d_in[2];    // [1024][1024]

  char* ws = (char*)d_ws;
  u16* x_bf = (u16*)(ws);
  u16* w_bf = (u16*)(ws + (size_t)(8u << 20));
  u16* wo_bf = (u16*)(ws + (size_t)(14u << 20));
  u16* qkv_bf = (u16*)(ws + (size_t)(16u << 20));
  u16* ao_bf = x_bf;  // alias (x consumed by then)

  cvt_f32_bf16<<<2048, 256, 0, stream>>>(x, x_bf, BL * DM / 4);
  cvt_f32_bf16<<<2048, 256, 0, stream>>>(wqkv, w_bf, QKV_N * DM / 4);
  cvt_f32_bf16<<<1024, 256, 0, stream>>>(wo, wo_bf, DM * DM / 4);

  dim3 g1(QKV_N / 128, BL / 128);  // (24, 32)
  gemm_bt<true><<<g1, 256, 0, stream>>>(x_bf, w_bf, (void*)qkv_bf, BL, QKV_N, DM);

  attn_fused<<<dim3(512), 256, 0, stream>>>(qkv_bf, ao_bf);

  dim3 g3(DM / 128, BL / 128);  // (8, 32)
  gemm_bt<false><<<g3, 256, 0, stream>>>(ao_bf, wo_bf, d_out, BL, DM, DM);
}

// Round 6
// 138.640 us; speedup vs baseline: 1.1798x; 1.1798x over previous
//
#include <hip/hip_runtime.h>
#include <hip/hip_bf16.h>
#include <cstdint>
#include <cstddef>

#define B_SZ 2
#define L_SEQ 2048
#define DM 1024
#define NH 16
#define HDIM 64
#define BL (B_SZ * L_SEQ)   // 4096 rows total
#define QKV_N (3 * DM)      // 3072

typedef __attribute__((ext_vector_type(4))) float f32x4;
typedef __attribute__((ext_vector_type(16))) float f32x16;
typedef __attribute__((ext_vector_type(8))) short bf16x8;
typedef __attribute__((ext_vector_type(4))) unsigned int u32x4;
typedef unsigned short u16;
typedef __attribute__((ext_vector_type(4))) unsigned short u16x4;

__device__ __forceinline__ float bf2f(u16 u) {
  union { unsigned int i; float f; } c; c.i = ((unsigned int)u) << 16; return c.f;
}
__device__ __forceinline__ u16 f2bf(float f) {
  union { float f; unsigned int i; } c; c.f = f;
  unsigned int r = c.i + 0x7fffu + ((c.i >> 16) & 1u);  // RNE
  return (u16)(r >> 16);
}

__device__ __forceinline__ void gload_lds16(const void* g, void* l) {
  __builtin_amdgcn_global_load_lds(
      (const __attribute__((address_space(1))) void*)g,
      (__attribute__((address_space(3))) void*)l, 16, 0, 0);
}

__device__ __forceinline__ f32x16 mfma32(bf16x8 a, bf16x8 b, f32x16 c) {
  return __builtin_amdgcn_mfma_f32_32x32x16_bf16(a, b, c, 0, 0, 0);
}

// packed f32 pair -> one u32 of 2 bf16 (lo in [15:0])
__device__ __forceinline__ unsigned cvtpk(float lo, float hi) {
  unsigned r;
  asm("v_cvt_pk_bf16_f32 %0, %1, %2" : "=v"(r) : "v"(lo), "v"(hi));
  return r;
}
// swap upper 32 lanes of a with lower 32 lanes of b (both updated)
__device__ __forceinline__ void plswap(unsigned& a, unsigned& b) {
  asm("v_permlane32_swap_b32 %0, %1" : "+v"(a), "+v"(b));
}

// 8 regs of a 32x32 D-layout group (rows (r&3)+8*(r>>2)+4*hi), BASE=0 or 8,
// -> bf16 B-fragment for mfma32 (verified R3).
template <int BASE>
__device__ __forceinline__ bf16x8 pack_bfrag(const f32x16& v) {
  unsigned a  = cvtpk(v[BASE + 0], v[BASE + 1]);
  unsigned a2 = cvtpk(v[BASE + 2], v[BASE + 3]);
  unsigned b  = cvtpk(v[BASE + 4], v[BASE + 5]);
  unsigned b2 = cvtpk(v[BASE + 6], v[BASE + 7]);
  plswap(a, b);
  plswap(a2, b2);
  u32x4 fw; fw[0] = a; fw[1] = a2; fw[2] = b; fw[3] = b2;
  return __builtin_bit_cast(bf16x8, fw);
}

// ---------------- fp32 -> bf16 convert ----------------
__global__ __launch_bounds__(256) void cvt_f32_bf16(const float* __restrict__ in,
                                                    u16* __restrict__ out, int n4) {
  int i = blockIdx.x * blockDim.x + threadIdx.x;
  const int stride = gridDim.x * blockDim.x;
  for (; i < n4; i += stride) {
    float4 v = ((const float4*)in)[i];
    u16x4 o;
    o[0] = f2bf(v.x); o[1] = f2bf(v.y); o[2] = f2bf(v.z); o[3] = f2bf(v.w);
    ((u16x4*)out)[i] = o;
  }
}

// ---------------- GEMM: C[M,N] = A[M,K] * B[N,K]^T (bf16 in, fp32 acc) ----
template <bool BF16_OUT>
__global__ __launch_bounds__(256) void gemm_bt(
    const u16* __restrict__ A, const u16* __restrict__ B,
    void* __restrict__ Cv, int M, int N, int K) {
  __shared__ u16 As[128 * 32];
  __shared__ u16 Bs[128 * 32];
  const int tid = threadIdx.x;
  const int lane = tid & 63, w = tid >> 6;
  const int lr = lane & 15, lg = lane >> 4;
  const int wr = w >> 1, wc = w & 1;
  const int bm = blockIdx.y * 128, bn = blockIdx.x * 128;

  f32x4 acc[4][4] = {};

  const int l4 = lane >> 2;
  const int csw = ((lane & 3) ^ ((lane >> 3) & 3)) * 8;
  const size_t aoff0 = (size_t)(bm + (w * 2 + 0) * 16 + l4) * K + csw;
  const size_t aoff1 = (size_t)(bm + (w * 2 + 1) * 16 + l4) * K + csw;
  const size_t boff0 = (size_t)(bn + (w * 2 + 0) * 16 + l4) * K + csw;
  const size_t boff1 = (size_t)(bn + (w * 2 + 1) * 16 + l4) * K + csw;
  u16* As0 = As + (w * 2 + 0) * 512;
  u16* As1 = As + (w * 2 + 1) * 512;
  u16* Bs0 = Bs + (w * 2 + 0) * 512;
  u16* Bs1 = Bs + (w * 2 + 1) * 512;
  const int sw_rd = (lr >> 1) & 3;

  for (int k0 = 0; k0 < K; k0 += 32) {
    gload_lds16(A + aoff0 + k0, As0);
    gload_lds16(A + aoff1 + k0, As1);
    gload_lds16(B + boff0 + k0, Bs0);
    gload_lds16(B + boff1 + k0, Bs1);
    __syncthreads();

    bf16x8 af[4], bfr[4];
#pragma unroll
    for (int mt = 0; mt < 4; ++mt) {
      const int row = wr * 64 + mt * 16 + lr;
      af[mt] = *(const bf16x8*)&As[row * 32 + ((lg ^ sw_rd) * 8)];
    }
#pragma unroll
    for (int nt = 0; nt < 4; ++nt) {
      const int row = wc * 64 + nt * 16 + lr;
      bfr[nt] = *(const bf16x8*)&Bs[row * 32 + ((lg ^ sw_rd) * 8)];
    }
#pragma unroll
    for (int mt = 0; mt < 4; ++mt)
#pragma unroll
      for (int nt = 0; nt < 4; ++nt)
        acc[mt][nt] = __builtin_amdgcn_mfma_f32_16x16x32_bf16(af[mt], bfr[nt],
                                                              acc[mt][nt], 0, 0, 0);
    __syncthreads();
  }

#pragma unroll
  for (int mt = 0; mt < 4; ++mt)
#pragma unroll
    for (int nt = 0; nt < 4; ++nt)
#pragma unroll
      for (int r = 0; r < 4; ++r) {
        const int row = bm + wr * 64 + mt * 16 + lg * 4 + r;
        const int col = bn + wc * 64 + nt * 16 + lr;
        if (BF16_OUT)
          ((u16*)Cv)[(size_t)row * N + col] = f2bf(acc[mt][nt][r]);
        else
          ((float*)Cv)[(size_t)row * N + col] = acc[mt][nt][r];
      }
}

// ---------------- fused causal flash attention, KV-chunked ----------------
// Grid 768 = 24 chunk-jobs x 32 bh. Job j -> (qt, kv-tile window [t0,t1)),
// heavy-first; qt>=8 q-tiles are split into 2 chunks that write fp32
// partials (O^T to d_out scratch, m/l to ws) merged by attn_combine.
// Block: 4 waves, wave w owns q rows [qt*128 + w*32, +32). KVBLK=64.
// Per-iter structure = R3 (best measured): reg-staged K+V, 1 barrier,
// swapped-operand 32x32 MFMA, in-register softmax.
__device__ const uint8_t JQT[24] = {15,14,13,12,11,10,9,8, 7, 15, 14,6, 13,5,
                                    12,4, 11,3, 10,2, 9,1, 8,0};
__device__ const uint8_t JT0[24] = {0,0,0,0,0,0,0,0, 0, 16, 16,0, 16,0,
                                    16,0, 16,0, 16,0, 16,0, 16,0};
__device__ const uint8_t JT1[24] = {16,16,16,16,16,16,16,16, 16, 32, 30,14, 28,12,
                                    26,10, 24,8, 22,6, 20,4, 18,2};

__global__ __launch_bounds__(256) void attn_fused(const u16* __restrict__ qkv,
                                                  u16* __restrict__ aout,
                                                  float* __restrict__ opart,
                                                  float2* __restrict__ mlb) {
  __shared__ u16 Kl[2][64 * 64];
  __shared__ u16 Vt[2][64 * 64];

  const int tid = threadIdx.x;
  const int lane = tid & 63, w = tid >> 6;
  const int l31 = lane & 31, hi = lane >> 5;
  const int id = (int)blockIdx.x;
  const int bh = id & 31, j = id >> 5;
  const int qt = JQT[j];
  const int t0 = JT0[j], t1 = JT1[j];
  const int b = bh >> 4, h = bh & 15;
  const u16* base = qkv + (size_t)b * L_SEQ * QKV_N;
  const int W = qt * 128 + w * 32;     // wave's first q row
  const int qrow = W + l31;            // this lane's q row

  // ---- K staging (reg): thread -> key row tid>>2, 2x16B slots
  const int krow = tid >> 2;
  const int ks0 = (tid & 3) * 2;
  const int kr7 = krow & 7;
  const u16* gpk_base = base + (size_t)krow * QKV_N + DM + h * HDIM + ks0 * 8;
  bf16x8 kr0, kr1;

  // ---- V staging (reg): thread -> d rows vd0, vd0+1; keys vkb*8..+7
  const int vd0 = (tid & 31) * 2;
  const int vkb = tid >> 5;            // 0..7
  const int vge = tid & 7;             // g(vd0)   = (vd0>>1)&7
  const int vgo = (tid & 7) ^ 4;       // g(vd0+1) = vge ^ 4
  const u16* gpv_base = base + (size_t)(vkb * 8) * QKV_N + 2 * DM + h * HDIM + vd0;
  unsigned int vtmp[8];

  auto issue_loads = [&](int t) {
    const u16* gpk = gpk_base + (size_t)t * 64 * QKV_N;
    kr0 = *(const bf16x8*)(gpk);
    kr1 = *(const bf16x8*)(gpk + 8);
    const u16* gpv = gpv_base + (size_t)t * 64 * QKV_N;
#pragma unroll
    for (int jj = 0; jj < 8; ++jj)
      vtmp[jj] = *(const unsigned int*)(gpv + (size_t)jj * QKV_N);
  };
  auto write_lds = [&](int buf) {
    *(bf16x8*)&Kl[buf][krow * 64 + ((ks0 ^ kr7) * 8)] = kr0;
    *(bf16x8*)&Kl[buf][krow * 64 + (((ks0 + 1) ^ kr7) * 8)] = kr1;
    u32x4 lo, hiw;
#pragma unroll
    for (int jj = 0; jj < 4; ++jj) {
      lo[jj]  = __builtin_amdgcn_perm(vtmp[2 * jj + 1], vtmp[2 * jj], 0x05040100u);
      hiw[jj] = __builtin_amdgcn_perm(vtmp[2 * jj + 1], vtmp[2 * jj], 0x07060302u);
    }
    *(u32x4*)&Vt[buf][vd0 * 64 + ((vkb ^ vge) * 8)] = lo;
    *(u32x4*)&Vt[buf][(vd0 + 1) * 64 + ((vkb ^ vgo) * 8)] = hiw;
  };

  // ---- Q B-frags: lane holds Q[qrow][dc*16 + hi*8 .. +7], scaled by
  // 0.125 * log2(e) so softmax uses exp2 directly.
  bf16x8 bq[4];
  {
    const u16* qp = base + (size_t)qrow * QKV_N + h * HDIM + hi * 8;
#pragma unroll
    for (int dc = 0; dc < 4; ++dc) {
      bf16x8 tq = *(const bf16x8*)(qp + dc * 16);
#pragma unroll
      for (int i = 0; i < 8; ++i)
        tq[i] = (short)f2bf(bf2f((u16)tq[i]) * 0.18033688f);
      bq[dc] = tq;
    }
  }

  f32x16 acc0 = {}, acc1 = {};  // O^T: d rows [0,32) and [32,64), col q
  float mrow = -1e30f, lrow = 0.f;

  const int vg = ((l31 >> 1) & 7) ^ ((l31 & 1) << 2);  // V^T read swizzle
  const int lsw = l31 & 7;                             // K read swizzle

  issue_loads(t0);
  write_lds(0);
  __syncthreads();

  for (int t = t0; t < t1; ++t) {
    const int cur = (t - t0) & 1;
    if (t + 1 < t1) issue_loads(t + 1);  // HBM latency hides under compute

    if (64 * t <= W + 31) {  // wave-uniform: this wave still needs keys
      // ---- S^T = K * Q^T over 2 key groups x 4 d-chunks
      f32x16 s0 = {}, s1 = {};
#pragma unroll
      for (int dc = 0; dc < 4; ++dc) {
        const int sl = ((dc * 2 + hi) ^ lsw) * 8;
        const bf16x8 k0 = *(const bf16x8*)&Kl[cur][l31 * 64 + sl];
        const bf16x8 k1 = *(const bf16x8*)&Kl[cur][(32 + l31) * 64 + sl];
        s0 = mfma32(k0, bq[dc], s0);
        s1 = mfma32(k1, bq[dc], s1);
      }

      // ---- causal mask (only the wave's diagonal-band tile)
      if (64 * t + 63 > W) {
#pragma unroll
        for (int r = 0; r < 16; ++r) {
          const int kg = t * 64 + (r & 3) + 8 * (r >> 2) + 4 * hi;
          if (kg > qrow) s0[r] = -1e30f;
          if (kg + 32 > qrow) s1[r] = -1e30f;
        }
      }

      // ---- tile max: pairwise trees, then cross-half
      float mx[8];
#pragma unroll
      for (int i = 0; i < 8; ++i)
        mx[i] = fmaxf(fmaxf(s0[i], s0[i + 8]), fmaxf(s1[i], s1[i + 8]));
#pragma unroll
      for (int i = 0; i < 4; ++i) mx[i] = fmaxf(mx[i], mx[i + 4]);
      float px = fmaxf(fmaxf(mx[0], mx[2]), fmaxf(mx[1], mx[3]));
      px = fmaxf(px, __shfl_xor(px, 32));

      // ---- defer-max rescale (T13, THR=8)
      if (!__all(px <= mrow + 8.f)) {
        const float mnew = fmaxf(mrow, px);
        const float alpha = exp2f(mrow - mnew);
        mrow = mnew;
        lrow *= alpha;
#pragma unroll
        for (int i = 0; i < 16; ++i) { acc0[i] *= alpha; acc1[i] *= alpha; }
      }

      // ---- P = exp2(S - m); sum as pairwise tree
#pragma unroll
      for (int r = 0; r < 16; ++r) {
        s0[r] = exp2f(s0[r] - mrow);
        s1[r] = exp2f(s1[r] - mrow);
      }
      float sm[8];
#pragma unroll
      for (int i = 0; i < 8; ++i)
        sm[i] = (s0[i] + s0[i + 8]) + (s1[i] + s1[i + 8]);
#pragma unroll
      for (int i = 0; i < 4; ++i) sm[i] += sm[i + 4];
      float rs = (sm[0] + sm[2]) + (sm[1] + sm[3]);
      rs += __shfl_xor(rs, 32);
      lrow += rs;

      // ---- P -> bf16 B-frags, in-register
      const bf16x8 pf0 = pack_bfrag<0>(s0);
      const bf16x8 pf1 = pack_bfrag<8>(s0);
      const bf16x8 pf2 = pack_bfrag<0>(s1);
      const bf16x8 pf3 = pack_bfrag<8>(s1);

      // ---- O^T += V^T * P^T
#pragma unroll
      for (int c = 0; c < 4; ++c) {
        const bf16x8 pf = c == 0 ? pf0 : c == 1 ? pf1 : c == 2 ? pf2 : pf3;
        const int sl = ((c * 2 + hi) ^ vg) * 8;
        const bf16x8 va = *(const bf16x8*)&Vt[cur][l31 * 64 + sl];
        const bf16x8 vb = *(const bf16x8*)&Vt[cur][(32 + l31) * 64 + sl];
        acc0 = mfma32(va, pf, acc0);
        acc1 = mfma32(vb, pf, acc1);
      }
    }

    if (t + 1 < t1) write_lds(((t + 1) - t0) & 1);
    __syncthreads();
  }

  if (qt >= 8) {
    // ---- split q-tile: write fp32 partial O^T [slot][64 d][128 q] + (m,l)
    const int c = (t0 == 16) ? 1 : 0;
    const int slot = ((qt - 8) * 2 + c) * 32 + bh;
    float* po = opart + (size_t)slot * 8192 + (w * 32 + l31);
#pragma unroll
    for (int i = 0; i < 16; ++i) {
      const int d0 = (i & 3) + 8 * (i >> 2) + 4 * hi;
      po[d0 * 128] = acc0[i];
      po[(d0 + 32) * 128] = acc1[i];
    }
    if (hi == 0) mlb[slot * 128 + w * 32 + l31] = make_float2(mrow, lrow);
  } else {
    // ---- direct: O = O^T / l, repack to d-contiguous frags, 16B stores
    const float inv = 1.f / lrow;
#pragma unroll
    for (int i = 0; i < 16; ++i) { acc0[i] *= inv; acc1[i] *= inv; }
    const bf16x8 of0 = pack_bfrag<0>(acc0);
    const bf16x8 of1 = pack_bfrag<8>(acc0);
    const bf16x8 of2 = pack_bfrag<0>(acc1);
    const bf16x8 of3 = pack_bfrag<8>(acc1);
    u16* op = aout + (size_t)(b * L_SEQ + qrow) * DM + h * HDIM + hi * 8;
    *(bf16x8*)(op + 0)  = of0;
    *(bf16x8*)(op + 16) = of1;
    *(bf16x8*)(op + 32) = of2;
    *(bf16x8*)(op + 48) = of3;
  }
}

// ---------------- combine two KV-chunk partials per q-row -----------------
// 512 partial-slot pairs cover qt 8..15. One wave per 64 q-rows.
__global__ __launch_bounds__(256) void attn_combine(
    const float* __restrict__ opart, const float2* __restrict__ mlb,
    u16* __restrict__ aout) {
  const int gw = ((int)blockIdx.x * 256 + (int)threadIdx.x) >> 6;  // 0..511
  const int lane = threadIdx.x & 63;
  const int u = gw >> 1, qh = gw & 1;
  const int qt = 8 + (u >> 5), bh = u & 31;
  const int b = bh >> 4, h = bh & 15;
  const int s1 = ((qt - 8) * 2) * 32 + bh, s2 = s1 + 32;
  const int q = qh * 64 + lane;  // 0..127 within q-tile
  const float2 ml1 = mlb[s1 * 128 + q];
  const float2 ml2 = mlb[s2 * 128 + q];
  const float m = fmaxf(ml1.x, ml2.x);
  const float a1 = exp2f(ml1.x - m), a2 = exp2f(ml2.x - m);
  const float invl = 1.f / (ml1.y * a1 + ml2.y * a2);
  const float c1 = a1 * invl, c2 = a2 * invl;
  const float* p1 = opart + (size_t)s1 * 8192 + q;
  const float* p2 = opart + (size_t)s2 * 8192 + q;
  const int qrow = qt * 128 + q;
  u16* op = aout + (size_t)(b * L_SEQ + qrow) * DM + h * HDIM;
#pragma unroll
  for (int d0 = 0; d0 < 64; d0 += 8) {
    u16x4 o0, o1;
#pragma unroll
    for (int jj = 0; jj < 4; ++jj) {
      o0[jj] = f2bf(p1[(d0 + jj) * 128] * c1 + p2[(d0 + jj) * 128] * c2);
      o1[jj] = f2bf(p1[(d0 + 4 + jj) * 128] * c1 + p2[(d0 + 4 + jj) * 128] * c2);
    }
    *(u16x4*)(op + d0) = o0;
    *(u16x4*)(op + d0 + 4) = o1;
  }
}

// ---------------- host launch ----------------
extern "C" void kernel_launch(void* const* d_in, const int* in_sizes, int n_in,
                              void* d_out, int out_size, void* d_ws, size_t ws_size,
                              hipStream_t stream) {
  (void)in_sizes; (void)n_in; (void)out_size; (void)ws_size;
  const float* x = (const float*)d_in[0];     // [4096][1024]
  const float* wqkv = (const float*)d_in[1];  // [3072][1024]
  const float* wo = (const float*)d_in[2];    // [1024][1024]

  char* ws = (char*)d_ws;
  // ws layout (40 MB): x_bf 8MB | w_bf 6MB | wo_bf 2MB | qkv_bf 24MB.
  // During attention: ml partials reuse the (dead) w_bf region; fp32 O^T
  // partials use d_out (16 MB, overwritten by the final GEMM afterwards);
  // attention output reuses x_bf.
  u16* x_bf = (u16*)(ws);
  u16* w_bf = (u16*)(ws + (size_t)(8u << 20));
  u16* wo_bf = (u16*)(ws + (size_t)(14u << 20));
  u16* qkv_bf = (u16*)(ws + (size_t)(16u << 20));
  u16* ao_bf = x_bf;                     // alias (x consumed by then)
  float* opart = (float*)d_out;          // 512 slots * 32KB = 16MB exactly
  float2* mlb = (float2*)(ws + (size_t)(8u << 20));  // 512KB in dead w_bf

  cvt_f32_bf16<<<2048, 256, 0, stream>>>(x, x_bf, BL * DM / 4);
  cvt_f32_bf16<<<2048, 256, 0, stream>>>(wqkv, w_bf, QKV_N * DM / 4);
  cvt_f32_bf16<<<1024, 256, 0, stream>>>(wo, wo_bf, DM * DM / 4);

  dim3 g1(QKV_N / 128, BL / 128);  // (24, 32)
  gemm_bt<true><<<g1, 256, 0, stream>>>(x_bf, w_bf, (void*)qkv_bf, BL, QKV_N, DM);

  attn_fused<<<dim3(768), 256, 0, stream>>>(qkv_bf, ao_bf, opart, mlb);
  attn_combine<<<dim3(128), 256, 0, stream>>>(opart, mlb, ao_bf);

  dim3 g3(DM / 128, BL / 128);  // (8, 32)
  gemm_bt<false><<<g3, 256, 0, stream>>>(ao_bf, wo_bf, d_out, BL, DM, DM);
}